// Round 4
// baseline (37.157 us; speedup 1.0000x reference)
//
#include <hip/hip_runtime.h>

// DICE multi-class loss.
//   output: [B=16, C=8, H=512, W=512] fp32
//   mask:   [B=16, H=512, W=512] int32 (labels 0..7)
// loss = 1 - sum_{b,c} dice(b,c) / (B*B)
//   dice = 2*(num+eps)/(den1+den2+eps)

#define BB 16
#define CC 8
#define HWPIX (512 * 512)
#define HW4 (HWPIX / 4)      // 65536 float4-quads per plane
#define BPB 32               // partial-blocks per batch image (was 128: reduction
                             // tail = 144 DS ops/wave serialized across 32 waves/CU
                             // ~= 11us; BPB=32 amortizes it 4x over 8 load iters)
#define QPB (HW4 / BPB)      // 2048 quads per block -> 8 iters/thread
#define NBLOCKS (BB * BPB)   // 512 blocks = 2/CU, 8 waves/CU (72KB loads in flight)

typedef float f32x4 __attribute__((ext_vector_type(4)));
typedef int i32x4 __attribute__((ext_vector_type(4)));

__device__ __forceinline__ float wred64(float x) {
#pragma unroll
    for (int o = 32; o > 0; o >>= 1) x += __shfl_down(x, o);
    return x;
}

__global__ __launch_bounds__(256, 2) void dice_partial(const float* __restrict__ out,
                                                       const int* __restrict__ mask,
                                                       float* __restrict__ ws) {
    const int b = blockIdx.x / BPB;
    const int blk = blockIdx.x % BPB;
    const f32x4* __restrict__ ov = (const f32x4*)(out + (size_t)b * CC * HWPIX);
    const i32x4* __restrict__ mv = (const i32x4*)(mask + (size_t)b * HWPIX);

    float num[CC], d1[CC], d2[CC];
#pragma unroll
    for (int c = 0; c < CC; ++c) { num[c] = 0.f; d1[c] = 0.f; d2[c] = 0.f; }

    const int q0 = blk * QPB;
#pragma unroll 2
    for (int q = q0 + threadIdx.x; q < q0 + QPB; q += 256) {
        const i32x4 m = __builtin_nontemporal_load(&mv[q]);
        f32x4 v[CC];
#pragma unroll
        for (int c = 0; c < CC; ++c) v[c] = __builtin_nontemporal_load(&ov[c * HW4 + q]);
#pragma unroll
        for (int c = 0; c < CC; ++c) {
            d1[c] += v[c].x * v[c].x + v[c].y * v[c].y + v[c].z * v[c].z + v[c].w * v[c].w;
            float hx = (m.x == c) ? 1.f : 0.f;
            float hy = (m.y == c) ? 1.f : 0.f;
            float hz = (m.z == c) ? 1.f : 0.f;
            float hw = (m.w == c) ? 1.f : 0.f;
            num[c] += hx * v[c].x + hy * v[c].y + hz * v[c].z + hw * v[c].w;
            d2[c] += hx + hy + hz + hw;
        }
    }

    const int lane = threadIdx.x & 63;
    const int wid = threadIdx.x >> 6;
    __shared__ float red[4][24];
#pragma unroll
    for (int c = 0; c < CC; ++c) {
        float a0 = wred64(num[c]);
        float a1 = wred64(d1[c]);
        float a2 = wred64(d2[c]);
        if (lane == 0) {
            red[wid][0 * 8 + c] = a0;
            red[wid][1 * 8 + c] = a1;
            red[wid][2 * 8 + c] = a2;
        }
    }
    __syncthreads();
    if (threadIdx.x < 24) {
        const int k = threadIdx.x;       // k = qy*8 + c
        const int qy = k >> 3;
        const int c = k & 7;
        float s = red[0][k] + red[1][k] + red[2][k] + red[3][k];
        ws[((qy * BB + b) * CC + c) * BPB + blk] = s;
    }
}

// 1024 threads: 8 threads per (b,c) pair; each reads one f32x4 per quantity.
__global__ __launch_bounds__(1024) void dice_final(const float* __restrict__ ws,
                                                   float* __restrict__ out) {
    const int t = threadIdx.x;
    const int g = t >> 3;        // (b,c) group 0..127
    const int sub = t & 7;
    const int b = g >> 3;
    const int c = g & 7;

    float acc[3];
#pragma unroll
    for (int qy = 0; qy < 3; ++qy) {
        const f32x4* p = (const f32x4*)(ws + ((qy * BB + b) * CC + c) * BPB);
        f32x4 v = p[sub];        // 8 subs x 4 floats = 32 partials
        acc[qy] = v.x + v.y + v.z + v.w;
    }
#pragma unroll
    for (int qy = 0; qy < 3; ++qy) {
#pragma unroll
        for (int o = 4; o > 0; o >>= 1) acc[qy] += __shfl_down(acc[qy], o, 8);
    }

    __shared__ float sm[128];
    __shared__ float sm2[2];
    if (sub == 0) {
        const float eps = 1e-7f;
        sm[g] = 2.f * (acc[0] + eps) / (acc[1] + acc[2] + eps);
    }
    __syncthreads();
    if (t < 128) {
        float x = wred64(sm[t]);
        if ((t & 63) == 0) sm2[t >> 6] = x;
    }
    __syncthreads();
    if (t == 0) out[0] = 1.f - (sm2[0] + sm2[1]) / ((float)BB * (float)BB);
}

extern "C" void kernel_launch(void* const* d_in, const int* in_sizes, int n_in,
                              void* d_out, int out_size, void* d_ws, size_t ws_size,
                              hipStream_t stream) {
    const float* out_probs = (const float*)d_in[0];
    const int* mask = (const int*)d_in[1];
    float* ws = (float*)d_ws;    // 3*16*8*32 floats = 48 KiB
    float* loss = (float*)d_out;

    dice_partial<<<NBLOCKS, 256, 0, stream>>>(out_probs, mask, ws);
    dice_final<<<1, 1024, 0, stream>>>(ws, loss);
}

// Round 5
// 30.660 us; speedup vs baseline: 1.2119x; 1.2119x over previous
//
#include <hip/hip_runtime.h>

// DICE multi-class loss.
//   output: [B=16, C=8, H=512, W=512] fp32
//   mask:   [B=16, H=512, W=512] int32 (labels 0..7)
// loss = 1 - sum_{b,c} dice(b,c) / (B*B)
//   dice = 2*(num+eps)/(den1+den2+eps)
//
// R4 lesson: 512 blocks (8 waves/CU) is latency-bound -> keep 2048 blocks.
// R5: replace ds_bpermute shuffle-reduce tail (144 DS ops/wave, serialized
// across 32 waves/CU on the single DS pipe) with DPP VALU reduction.

#define BB 16
#define CC 8
#define HWPIX (512 * 512)
#define HW4 (HWPIX / 4)      // 65536 float4-quads per plane
#define BPB 128              // partial-blocks per batch image
#define QPB (HW4 / BPB)      // 512 quads per block -> 2 iters/thread
#define NBLOCKS (BB * BPB)   // 2048 blocks = 8/CU, 32 waves/CU

typedef float f32x4 __attribute__((ext_vector_type(4)));
typedef int i32x4 __attribute__((ext_vector_type(4)));

// ---- DPP wave64 sum (VALU pipe only, no DS ops) ----
// row_shr:1/2/4/8 with bound_ctrl=1 (0-fill) reduces each 16-lane row into its
// last lane; row_bcast:15 folds row0->row1 / row2->row3; row_bcast:31 folds
// rows 0-1 -> rows 2-3. Total ends in lane 63.
template <int CTRL>
__device__ __forceinline__ float dpp_add(float x) {
    int yi = __builtin_amdgcn_update_dpp(0, __float_as_int(x), CTRL, 0xf, 0xf, true);
    return x + __int_as_float(yi);
}

__device__ __forceinline__ float wave_sum63(float x) {
    x = dpp_add<0x111>(x);   // row_shr:1
    x = dpp_add<0x112>(x);   // row_shr:2
    x = dpp_add<0x114>(x);   // row_shr:4
    x = dpp_add<0x118>(x);   // row_shr:8
    x = dpp_add<0x142>(x);   // row_bcast:15
    x = dpp_add<0x143>(x);   // row_bcast:31
    return x;                // lane 63 holds the wave total
}

__global__ __launch_bounds__(256) void dice_partial(const float* __restrict__ out,
                                                    const int* __restrict__ mask,
                                                    float* __restrict__ ws) {
    const int b = blockIdx.x / BPB;
    const int blk = blockIdx.x % BPB;
    const f32x4* __restrict__ ov = (const f32x4*)(out + (size_t)b * CC * HWPIX);
    const i32x4* __restrict__ mv = (const i32x4*)(mask + (size_t)b * HWPIX);

    float num[CC], d1[CC], d2[CC];
#pragma unroll
    for (int c = 0; c < CC; ++c) { num[c] = 0.f; d1[c] = 0.f; d2[c] = 0.f; }

    const int q0 = blk * QPB;
    for (int q = q0 + threadIdx.x; q < q0 + QPB; q += 256) {
        const i32x4 m = __builtin_nontemporal_load(&mv[q]);
        f32x4 v[CC];
#pragma unroll
        for (int c = 0; c < CC; ++c) v[c] = __builtin_nontemporal_load(&ov[c * HW4 + q]);
#pragma unroll
        for (int c = 0; c < CC; ++c) {
            d1[c] += v[c].x * v[c].x + v[c].y * v[c].y + v[c].z * v[c].z + v[c].w * v[c].w;
            float hx = (m.x == c) ? 1.f : 0.f;
            float hy = (m.y == c) ? 1.f : 0.f;
            float hz = (m.z == c) ? 1.f : 0.f;
            float hw = (m.w == c) ? 1.f : 0.f;
            num[c] += hx * v[c].x + hy * v[c].y + hz * v[c].z + hw * v[c].w;
            d2[c] += hx + hy + hz + hw;
        }
    }

    const int lane = threadIdx.x & 63;
    const int wid = threadIdx.x >> 6;
    __shared__ float red[4][24];
#pragma unroll
    for (int c = 0; c < CC; ++c) {
        float a0 = wave_sum63(num[c]);
        float a1 = wave_sum63(d1[c]);
        float a2 = wave_sum63(d2[c]);
        if (lane == 63) {
            red[wid][0 * 8 + c] = a0;
            red[wid][1 * 8 + c] = a1;
            red[wid][2 * 8 + c] = a2;
        }
    }
    __syncthreads();
    if (threadIdx.x < 24) {
        const int k = threadIdx.x;       // k = qy*8 + c
        const int qy = k >> 3;
        const int c = k & 7;
        float s = red[0][k] + red[1][k] + red[2][k] + red[3][k];
        // partial layout: ws[((qy*BB + b)*CC + c)*BPB + blk]
        ws[((qy * BB + b) * CC + c) * BPB + blk] = s;
    }
}

// 1024 threads: 8 threads per (b,c) pair, 4 f32x4 loads each.
__global__ __launch_bounds__(1024) void dice_final(const float* __restrict__ ws,
                                                   float* __restrict__ out) {
    const int t = threadIdx.x;
    const int g = t >> 3;        // (b,c) group 0..127
    const int sub = t & 7;
    const int b = g >> 3;
    const int c = g & 7;

    float acc[3] = {0.f, 0.f, 0.f};   // num, d1, d2
#pragma unroll
    for (int qy = 0; qy < 3; ++qy) {
        const f32x4* p = (const f32x4*)(ws + ((qy * BB + b) * CC + c) * BPB);
#pragma unroll
        for (int i = 0; i < BPB / (8 * 4); ++i) {   // 4 f32x4 per thread
            f32x4 v = p[sub + i * 8];
            acc[qy] += v.x + v.y + v.z + v.w;
        }
    }
#pragma unroll
    for (int qy = 0; qy < 3; ++qy) {
#pragma unroll
        for (int o = 4; o > 0; o >>= 1) acc[qy] += __shfl_down(acc[qy], o, 8);
    }

    __shared__ float sm[128];
    __shared__ float sm2[2];
    if (sub == 0) {
        const float eps = 1e-7f;
        sm[g] = 2.f * (acc[0] + eps) / (acc[1] + acc[2] + eps);
    }
    __syncthreads();
    if (t < 128) {
        float x = sm[t];
#pragma unroll
        for (int o = 32; o > 0; o >>= 1) x += __shfl_down(x, o);
        if ((t & 63) == 0) sm2[t >> 6] = x;
    }
    __syncthreads();
    if (t == 0) out[0] = 1.f - (sm2[0] + sm2[1]) / ((float)BB * (float)BB);
}

extern "C" void kernel_launch(void* const* d_in, const int* in_sizes, int n_in,
                              void* d_out, int out_size, void* d_ws, size_t ws_size,
                              hipStream_t stream) {
    const float* out_probs = (const float*)d_in[0];
    const int* mask = (const int*)d_in[1];
    float* ws = (float*)d_ws;    // 3*16*8*128 floats = 192 KiB
    float* loss = (float*)d_out;

    dice_partial<<<NBLOCKS, 256, 0, stream>>>(out_probs, mask, ws);
    dice_final<<<1, 1024, 0, stream>>>(ws, loss);
}